// Round 4
// baseline (156.289 us; speedup 1.0000x reference)
//
#include <hip/hip_runtime.h>
#include <math.h>

// B=64, S=512, H=1024
#define BB 64
#define SS 512
#define HH 1024
#define K3 3072
#define KSPLIT 16
#define KCHUNK 192          // K3 / KSPLIT
#define JTILE 32            // j-columns per block (8 waves x RJ)
#define RJ 4                // j-columns per wave
#define LDS_PAD 196         // feats row stride in floats (16B-aligned, 2-way banks = free)

// ---------------- Kernel 1: means only --------------------------------------
// feats[b, 1024:2048] = subj-mean, feats[b, 2048:3072] = obj-mean.
// (first-token section is read directly from hs by kernel 2.)
// grid 128 = (64 b) x (2 feat), 512 threads = 8 waves.
// wave w takes rows s0+w, s0+w+8, ... (serial depth <= 4); LDS reduce.
__global__ __launch_bounds__(512) void feats_kernel(
    const float* __restrict__ hs,     // (B,S,H)
    const int*   __restrict__ subj,   // (B,2)
    const int*   __restrict__ obj,    // (B,2)
    float*       __restrict__ feats)  // (B,3H)
{
    const int bid  = blockIdx.x;
    const int tid  = threadIdx.x;
    const int b    = bid >> 1;
    const int feat = bid & 1;
    const int* rng = feat ? obj : subj;
    const int s0 = rng[2 * b], s1 = rng[2 * b + 1];

    const int w    = tid >> 6;        // wave 0..7
    const int lane = tid & 63;

    __shared__ float4 lds[8][256];    // 8 wave-partials of H floats (32 KB)

    const float4* base = (const float4*)(hs + (size_t)b * SS * HH);

    float4 acc[4];                    // q -> float4 index q*64+lane
    #pragma unroll
    for (int q = 0; q < 4; ++q) acc[q] = make_float4(0.f, 0.f, 0.f, 0.f);

    for (int s = s0 + w; s < s1; s += 8) {
        const float4* row = base + (size_t)s * (HH / 4);
        #pragma unroll
        for (int q = 0; q < 4; ++q) {
            float4 v = row[q * 64 + lane];
            acc[q].x += v.x; acc[q].y += v.y; acc[q].z += v.z; acc[q].w += v.w;
        }
    }

    #pragma unroll
    for (int q = 0; q < 4; ++q)
        lds[w][q * 64 + lane] = acc[q];
    __syncthreads();

    if (tid < 256) {
        float4 s = lds[0][tid];
        #pragma unroll
        for (int p = 1; p < 8; ++p) {
            float4 v = lds[p][tid];
            s.x += v.x; s.y += v.y; s.z += v.z; s.w += v.w;
        }
        const float inv = 1.0f / fmaxf((float)(s1 - s0), 1.0f);
        s.x *= inv; s.y *= inv; s.z *= inv; s.w *= inv;
        ((float4*)(feats + (size_t)b * K3 + (1 + feat) * HH))[tid] = s;
    }
}

// ---------------- Kernel 2: GEMM partials + last-block tail -----------------
// part[p][j][b] = sum_{k in chunk p} feats[b][k] * W[j][k]
// grid 512 = (32 j-groups) x (16 k-parts), 512 threads = 8 waves.
// lane = b; wave handles RJ=4 j-columns (wave-uniform W rows -> s_load);
// feats chunk staged once in LDS per block; k<1024 staged straight from hs.
// Last block per j-group reduces the 16 partials + bias + tanh.
__global__ __launch_bounds__(512) void gemm_kernel(
    const float* __restrict__ hs,     // (B,S,H)  (row 0 = first-token section)
    const float* __restrict__ feats,  // (B,3H)   (sections 1,2 valid)
    const float* __restrict__ W,      // (H,3H) row-major
    const float* __restrict__ bias,   // (H)
    float*       __restrict__ part,   // (KSPLIT, H, B)
    int*         __restrict__ counters, // (32) zeroed per call
    float*       __restrict__ out)    // (B,H)
{
    __shared__ float lds[BB][LDS_PAD];    // 49 KB
    __shared__ int is_last;

    const int bid   = blockIdx.x;
    const int kpart = bid & 15;
    const int jg    = bid >> 4;           // 0..31
    const int kbase = kpart * KCHUNK;
    const int tid   = threadIdx.x;

    // stage [:, kbase:kbase+192] -> lds[b][k]; 8 threads per row, 6 f4 each.
    // k < 1024 comes straight from hs[b,0,:]; k >= 1024 from feats.
    {
        const int b = tid >> 3, q = tid & 7;
        const float4* hsrc = (const float4*)(hs + (size_t)b * SS * HH);
        const float4* fsrc = (const float4*)(feats + (size_t)b * K3);
        #pragma unroll
        for (int i = 0; i < 6; ++i) {
            const int f4i = i * 8 + q;
            const int k = kbase + f4i * 4;           // f4-aligned; 1024 boundary f4-aligned
            const float4* src = (k < 1024) ? (hsrc + (k >> 2)) : (fsrc + (k >> 2));
            *(float4*)&lds[b][f4i * 4] = *src;
        }
    }
    __syncthreads();

    const int w    = __builtin_amdgcn_readfirstlane(tid >> 6);  // 0..7, uniform
    const int lane = tid & 63;                                  // = batch b
    const int j0   = jg * JTILE + w * RJ;

    float acc[RJ];
    #pragma unroll
    for (int jj = 0; jj < RJ; ++jj) acc[jj] = 0.f;

    const float* wp = W + (size_t)j0 * K3 + kbase;  // uniform -> s_load

    #pragma unroll 4
    for (int kk = 0; kk < KCHUNK; kk += 4) {
        const float4 f = *(const float4*)&lds[lane][kk];
        #pragma unroll
        for (int jj = 0; jj < RJ; ++jj) {
            const float4 wv = *(const float4*)(wp + (size_t)jj * K3 + kk);
            acc[jj] = fmaf(f.x, wv.x, acc[jj]);
            acc[jj] = fmaf(f.y, wv.y, acc[jj]);
            acc[jj] = fmaf(f.z, wv.z, acc[jj]);
            acc[jj] = fmaf(f.w, wv.w, acc[jj]);
        }
    }

    float* pp = part + ((size_t)kpart * HH + j0) * BB + lane;
    #pragma unroll
    for (int jj = 0; jj < RJ; ++jj)
        pp[jj * BB] = acc[jj];                      // coalesced over lanes

    // ---- last-block-per-jg tail reduction ----
    __threadfence();                                 // release partials (device scope)
    __syncthreads();                                 // all waves' stores+fences done
    if (tid == 0)
        is_last = (atomicAdd(&counters[jg], 1) == KSPLIT - 1);
    __syncthreads();
    if (!is_last) return;
    __threadfence();                                 // acquire other blocks' partials

    // 32 j x 64 b = 2048 outputs, 512 threads -> 4 each (bb fast: coalesced reads)
    #pragma unroll
    for (int r = 0; r < 4; ++r) {
        const int idx = r * 512 + tid;
        const int jj  = idx >> 6;                    // 0..31
        const int bb  = idx & 63;
        const int j   = jg * JTILE + jj;
        float s = 0.f;
        #pragma unroll
        for (int p = 0; p < KSPLIT; ++p)
            s += part[((size_t)p * HH + j) * BB + bb];
        out[(size_t)bb * HH + j] = tanhf(s + bias[j]);
    }
}

extern "C" void kernel_launch(void* const* d_in, const int* in_sizes, int n_in,
                              void* d_out, int out_size, void* d_ws, size_t ws_size,
                              hipStream_t stream) {
    const float* hs   = (const float*)d_in[0];  // (B,S,H) fp32
    const int*   subj = (const int*)d_in[1];    // (B,2) int32
    const int*   obj  = (const int*)d_in[2];    // (B,2) int32
    const float* W    = (const float*)d_in[3];  // (H,3H) fp32
    const float* bias = (const float*)d_in[4];  // (H) fp32
    float*       out  = (float*)d_out;          // (B,H) fp32

    float* feats    = (float*)d_ws;                              // 768 KB
    float* part     = (float*)((char*)d_ws + (1 << 20));         // 4 MB at +1 MB
    int*   counters = (int*)((char*)d_ws + 5 * (1 << 20));       // 128 B at +5 MB

    hipMemsetAsync(counters, 0, 32 * sizeof(int), stream);
    feats_kernel<<<BB * 2, 512, 0, stream>>>(hs, subj, obj, feats);
    gemm_kernel<<<JTILE * KSPLIT, 512, 0, stream>>>(hs, feats, W, bias, part,
                                                    counters, out);
}

// Round 5
// 40.915 us; speedup vs baseline: 3.8198x; 3.8198x over previous
//
#include <hip/hip_runtime.h>
#include <math.h>

// B=64, S=512, H=1024
#define BB 64
#define SS 512
#define HH 1024
#define K3 3072
#define KSPLIT 16
#define KCHUNK 192          // K3 / KSPLIT
#define RJ 4                // j-columns per wave
#define JTILE 16            // j-columns per block (4 waves x RJ)

// ---------------- Kernel 1: means only --------------------------------------
// feats[b, 1024:2048] = subj-mean, feats[b, 2048:3072] = obj-mean.
// (first-token section is read directly from hs by kernel 2.)
// grid 128 = (64 b) x (2 feat), 512 threads = 8 waves.
// wave w takes rows s0+w, s0+w+8, ... (serial depth <= 4); LDS reduce.
__global__ __launch_bounds__(512) void feats_kernel(
    const float* __restrict__ hs,     // (B,S,H)
    const int*   __restrict__ subj,   // (B,2)
    const int*   __restrict__ obj,    // (B,2)
    float*       __restrict__ feats)  // (B,3H)
{
    const int bid  = blockIdx.x;
    const int tid  = threadIdx.x;
    const int b    = bid >> 1;
    const int feat = bid & 1;
    const int* rng = feat ? obj : subj;
    const int s0 = rng[2 * b], s1 = rng[2 * b + 1];

    const int w    = tid >> 6;        // wave 0..7
    const int lane = tid & 63;

    __shared__ float4 lds[8][256];    // 8 wave-partials of H floats (32 KB)

    const float4* base = (const float4*)(hs + (size_t)b * SS * HH);

    float4 acc[4];                    // q -> float4 index q*64+lane
    #pragma unroll
    for (int q = 0; q < 4; ++q) acc[q] = make_float4(0.f, 0.f, 0.f, 0.f);

    for (int s = s0 + w; s < s1; s += 8) {
        const float4* row = base + (size_t)s * (HH / 4);
        #pragma unroll
        for (int q = 0; q < 4; ++q) {
            float4 v = row[q * 64 + lane];
            acc[q].x += v.x; acc[q].y += v.y; acc[q].z += v.z; acc[q].w += v.w;
        }
    }

    #pragma unroll
    for (int q = 0; q < 4; ++q)
        lds[w][q * 64 + lane] = acc[q];
    __syncthreads();

    if (tid < 256) {
        float4 s = lds[0][tid];
        #pragma unroll
        for (int p = 1; p < 8; ++p) {
            float4 v = lds[p][tid];
            s.x += v.x; s.y += v.y; s.z += v.z; s.w += v.w;
        }
        const float inv = 1.0f / fmaxf((float)(s1 - s0), 1.0f);
        s.x *= inv; s.y *= inv; s.z *= inv; s.w *= inv;
        ((float4*)(feats + (size_t)b * K3 + (1 + feat) * HH))[tid] = s;
    }
}

// ---------------- Kernel 2: GEMM partials -----------------------------------
// part[p][j][b] = sum_{k in chunk p} feats[b][k] * W[j][k]
// grid 1024 = (64 j-groups) x (16 k-parts), 256 threads = 4 waves.
// lane = b (64 batches); wave owns RJ=4 j-columns.
//   W rows are wave-uniform -> merged s_load_dwordx8/x16 (scalar pipe, one
//   lgkmcnt drain per 64 FMAs).
//   feats: each lane reads its own 64B line per 16-k body (no LDS at all;
//   k<1024 straight from hs[b,0,:], else from feats buffer).
// 4096 waves = 4 waves/SIMD.
__global__ __launch_bounds__(256) void gemm_kernel(
    const float* __restrict__ hs,     // (B,S,H)  (row 0 = first-token section)
    const float* __restrict__ feats,  // (B,3H)   (sections 1,2 valid)
    const float* __restrict__ W,      // (H,3H) row-major
    float*       __restrict__ part)   // (KSPLIT, H, B)
{
    const int bid   = blockIdx.x;
    const int kp    = bid & 15;
    const int jg    = bid >> 4;             // 0..63
    const int kbase = kp * KCHUNK;
    const int tid   = threadIdx.x;

    const int w    = __builtin_amdgcn_readfirstlane(tid >> 6);  // 0..3, uniform
    const int lane = tid & 63;                                  // = batch b
    const int j0   = jg * JTILE + w * RJ;

    const float* wp      = W + (size_t)j0 * K3 + kbase;         // uniform
    const float* fsrc_hs = hs + (size_t)lane * SS * HH;         // k < 1024
    const float* fsrc_f  = feats + (size_t)lane * K3;           // k >= 1024

    float acc[RJ];
    #pragma unroll
    for (int jj = 0; jj < RJ; ++jj) acc[jj] = 0.f;

    #pragma unroll 2
    for (int body = 0; body < KCHUNK / 16; ++body) {            // 12 bodies
        const int k = kbase + body * 16;                        // 16-aligned
        const float* fs = (k < 1024) ? (fsrc_hs + k) : (fsrc_f + k);

        float4 f[4];                                            // one 64B line
        #pragma unroll
        for (int q = 0; q < 4; ++q)
            f[q] = *(const float4*)(fs + 4 * q);

        #pragma unroll
        for (int jj = 0; jj < RJ; ++jj) {
            const float* wr = wp + (size_t)jj * K3 + body * 16; // uniform, 64B
            #pragma unroll
            for (int q = 0; q < 4; ++q) {
                const float4 wv = *(const float4*)(wr + 4 * q);
                acc[jj] = fmaf(f[q].x, wv.x, acc[jj]);
                acc[jj] = fmaf(f[q].y, wv.y, acc[jj]);
                acc[jj] = fmaf(f[q].z, wv.z, acc[jj]);
                acc[jj] = fmaf(f[q].w, wv.w, acc[jj]);
            }
        }
    }

    float* pp = part + ((size_t)kp * HH + j0) * BB + lane;
    #pragma unroll
    for (int jj = 0; jj < RJ; ++jj)
        pp[jj * BB] = acc[jj];                      // coalesced over lanes
}

// ---------------- Kernel 3: reduce k-parts + bias + tanh --------------------
// grid 256 x 256: block covers 4 j-columns x 64 b.
__global__ __launch_bounds__(256) void reduce_kernel(
    const float* __restrict__ part,   // (KSPLIT, H, B)
    const float* __restrict__ bias,   // (H)
    float*       __restrict__ out)    // (B,H)
{
    const int t = threadIdx.x;
    const int j = blockIdx.x * 4 + (t >> 6);
    const int b = t & 63;
    float s = 0.f;
    #pragma unroll
    for (int p = 0; p < KSPLIT; ++p)
        s += part[((size_t)p * HH + j) * BB + b];   // coalesced over lanes
    out[(size_t)b * HH + j] = tanhf(s + bias[j]);
}

extern "C" void kernel_launch(void* const* d_in, const int* in_sizes, int n_in,
                              void* d_out, int out_size, void* d_ws, size_t ws_size,
                              hipStream_t stream) {
    const float* hs   = (const float*)d_in[0];  // (B,S,H) fp32
    const int*   subj = (const int*)d_in[1];    // (B,2) int32
    const int*   obj  = (const int*)d_in[2];    // (B,2) int32
    const float* W    = (const float*)d_in[3];  // (H,3H) fp32
    const float* bias = (const float*)d_in[4];  // (H) fp32
    float*       out  = (float*)d_out;          // (B,H) fp32

    float* feats = (float*)d_ws;                            // 768 KB
    float* part  = (float*)((char*)d_ws + (1 << 20));       // 4 MB at +1 MB

    feats_kernel<<<BB * 2, 512, 0, stream>>>(hs, subj, obj, feats);
    gemm_kernel<<<(HH / JTILE) * KSPLIT, 256, 0, stream>>>(hs, feats, W, part);
    reduce_kernel<<<HH / 4, 256, 0, stream>>>(part, bias, out);
}

// Round 6
// 37.970 us; speedup vs baseline: 4.1161x; 1.0776x over previous
//
#include <hip/hip_runtime.h>
#include <math.h>

// B=64, S=512, H=1024
#define BB 64
#define SS 512
#define HH 1024
#define K3 3072
#define KSPLIT 16
#define KCHUNK 192          // K3 / KSPLIT
#define RJ 8                // j-columns per wave
#define JTILE 32            // j-columns per block (4 waves x RJ)
#define LDS_PAD 196         // feats row stride in floats (stride%32==4 -> b128 conflict-free)

typedef float v2f __attribute__((ext_vector_type(2)));

// ---------------- Kernel 1: means only --------------------------------------
// feats[b, 1024:2048] = subj-mean, feats[b, 2048:3072] = obj-mean.
// (first-token section is read directly from hs by kernel 2.)
// grid 256 = (64 b) x (2 feat) x (2 h-half), 512 threads = 8 waves.
// wave w takes rows s0+w, s0+w+8, ... (serial depth <= 4); LDS reduce.
__global__ __launch_bounds__(512) void feats_kernel(
    const float* __restrict__ hs,     // (B,S,H)
    const int*   __restrict__ subj,   // (B,2)
    const int*   __restrict__ obj,    // (B,2)
    float*       __restrict__ feats)  // (B,3H)
{
    const int bid  = blockIdx.x;
    const int tid  = threadIdx.x;
    const int b    = bid >> 2;
    const int feat = (bid >> 1) & 1;
    const int half = bid & 1;
    const int* rng = feat ? obj : subj;
    const int s0 = rng[2 * b], s1 = rng[2 * b + 1];

    const int w    = tid >> 6;        // wave 0..7
    const int lane = tid & 63;

    __shared__ float4 lds[8][128];    // 8 wave-partials of 512 floats (16 KB)

    const float4* base = (const float4*)(hs + (size_t)b * SS * HH + half * (HH / 2));

    float4 acc[2];
    #pragma unroll
    for (int q = 0; q < 2; ++q) acc[q] = make_float4(0.f, 0.f, 0.f, 0.f);

    for (int s = s0 + w; s < s1; s += 8) {
        const float4* row = base + (size_t)s * (HH / 4);
        #pragma unroll
        for (int q = 0; q < 2; ++q) {
            float4 v = row[q * 64 + lane];
            acc[q].x += v.x; acc[q].y += v.y; acc[q].z += v.z; acc[q].w += v.w;
        }
    }

    #pragma unroll
    for (int q = 0; q < 2; ++q)
        lds[w][q * 64 + lane] = acc[q];
    __syncthreads();

    if (tid < 128) {
        float4 s = lds[0][tid];
        #pragma unroll
        for (int p = 1; p < 8; ++p) {
            float4 v = lds[p][tid];
            s.x += v.x; s.y += v.y; s.z += v.z; s.w += v.w;
        }
        const float inv = 1.0f / fmaxf((float)(s1 - s0), 1.0f);
        s.x *= inv; s.y *= inv; s.z *= inv; s.w *= inv;
        ((float4*)(feats + (size_t)b * K3 + (1 + feat) * HH + half * (HH / 2)))[tid] = s;
    }
}

// ---------------- Kernel 2: GEMM partials -----------------------------------
// part[p][j][b] = sum_{k in chunk p} feats[b][k] * W[j][k]
// grid 512 = (32 j-groups) x (16 k-parts), 256 threads = 4 waves.
// lane = b (64 batches); wave owns RJ=8 j-columns.
//   feats chunk staged in LDS (k<1024 straight from hs row 0) -> ds_read_b128
//   (lgkmcnt, in-order, counted waits).
//   W via VECTOR global loads (uniform addr -> 1 transaction broadcast) on
//   vmcnt -- no readfirstlane, so the pointer stays formally divergent and
//   the compiler cannot fall back to out-of-order s_load + lgkmcnt(0) drains.
//   FMAs packed as float2 -> v_pk_fma_f32.
__global__ __launch_bounds__(256) void gemm_kernel(
    const float* __restrict__ hs,     // (B,S,H)  (row 0 = first-token section)
    const float* __restrict__ feats,  // (B,3H)   (sections 1,2 valid)
    const float* __restrict__ W,      // (H,3H) row-major
    float*       __restrict__ part)   // (KSPLIT, H, B)
{
    __shared__ float lds[BB][LDS_PAD];    // 49 KB

    const int bid   = blockIdx.x;
    const int kp    = bid & 15;
    const int jg    = bid >> 4;           // 0..31
    const int kbase = kp * KCHUNK;
    const int tid   = threadIdx.x;

    // stage [:, kbase:kbase+192] -> lds[b][k]; 4 threads per row, 12 f4 each.
    {
        const int b = tid >> 2, q = tid & 3;
        const float4* hsrc = (const float4*)(hs + (size_t)b * SS * HH);
        const float4* fsrc = (const float4*)(feats + (size_t)b * K3);
        #pragma unroll
        for (int i = 0; i < 12; ++i) {
            const int f4i = i * 4 + q;
            const int k = kbase + f4i * 4;           // f4-aligned; 1024 boundary f4-aligned
            const float4* src = (k < 1024) ? (hsrc + (k >> 2)) : (fsrc + (k >> 2));
            *(float4*)&lds[b][f4i * 4] = *src;
        }
    }
    __syncthreads();

    const int w    = tid >> 6;            // intentionally NOT readfirstlane
    const int lane = tid & 63;            // = batch b
    const int j0   = jg * JTILE + w * RJ;

    const float* wp = W + (size_t)j0 * K3 + kbase;

    v2f acc[RJ];
    #pragma unroll
    for (int jj = 0; jj < RJ; ++jj) acc[jj] = (v2f)(0.f);

    #pragma unroll 2
    for (int kk = 0; kk < KCHUNK; kk += 4) {
        const float4 f = *(const float4*)&lds[lane][kk];
        const v2f f01 = { f.x, f.y };
        const v2f f23 = { f.z, f.w };
        #pragma unroll
        for (int jj = 0; jj < RJ; ++jj) {
            const float4 wv = *(const float4*)(wp + (size_t)jj * K3 + kk);
            const v2f w01 = { wv.x, wv.y };
            const v2f w23 = { wv.z, wv.w };
            acc[jj] = __builtin_elementwise_fma(w01, f01, acc[jj]);
            acc[jj] = __builtin_elementwise_fma(w23, f23, acc[jj]);
        }
    }

    float* pp = part + ((size_t)kp * HH + j0) * BB + lane;
    #pragma unroll
    for (int jj = 0; jj < RJ; ++jj)
        pp[jj * BB] = acc[jj].x + acc[jj].y;        // coalesced over lanes
}

// ---------------- Kernel 3: reduce k-parts + bias + tanh --------------------
// grid 256 x 256: block covers 4 j-columns x 64 b.
__global__ __launch_bounds__(256) void reduce_kernel(
    const float* __restrict__ part,   // (KSPLIT, H, B)
    const float* __restrict__ bias,   // (H)
    float*       __restrict__ out)    // (B,H)
{
    const int t = threadIdx.x;
    const int j = blockIdx.x * 4 + (t >> 6);
    const int b = t & 63;
    float s = 0.f;
    #pragma unroll
    for (int p = 0; p < KSPLIT; ++p)
        s += part[((size_t)p * HH + j) * BB + b];   // coalesced over lanes
    out[(size_t)b * HH + j] = tanhf(s + bias[j]);
}

extern "C" void kernel_launch(void* const* d_in, const int* in_sizes, int n_in,
                              void* d_out, int out_size, void* d_ws, size_t ws_size,
                              hipStream_t stream) {
    const float* hs   = (const float*)d_in[0];  // (B,S,H) fp32
    const int*   subj = (const int*)d_in[1];    // (B,2) int32
    const int*   obj  = (const int*)d_in[2];    // (B,2) int32
    const float* W    = (const float*)d_in[3];  // (H,3H) fp32
    const float* bias = (const float*)d_in[4];  // (H) fp32
    float*       out  = (float*)d_out;          // (B,H) fp32

    float* feats = (float*)d_ws;                            // 768 KB
    float* part  = (float*)((char*)d_ws + (1 << 20));       // 4 MB at +1 MB

    feats_kernel<<<BB * 4, 512, 0, stream>>>(hs, subj, obj, feats);
    gemm_kernel<<<(HH / JTILE) * KSPLIT, 256, 0, stream>>>(hs, feats, W, part);
    reduce_kernel<<<HH / 4, 256, 0, stream>>>(part, bias, out);
}

// Round 7
// 26.313 us; speedup vs baseline: 5.9397x; 1.4430x over previous
//
#include <hip/hip_runtime.h>
#include <math.h>

// B=64, S=512, H=1024
#define BB 64
#define SS 512
#define HH 1024
#define K3 3072
#define KSPLIT 16
#define KCHUNK 192          // K3 / KSPLIT -> 48 float4-rows per chunk
#define RJ 4                // j-columns per wave
#define JTILE 16            // j-columns per block (4 waves x RJ)

// Transposed packed feats: FP[r][b] (float4), r = k/4 in [0,768), b in [0,64).
//   r <  256 : first-token  (k < 1024)
//   256..511 : subj-mean    (1024 <= k < 2048)
//   512..767 : obj-mean     (2048 <= k < 3072)
// Lane=b then reads feats coalesced (global_load_dwordx4, 1 KB/wave/row).

// ---------------- Kernel 1: build FP ----------------------------------------
// grid 160 x 512 threads:
//   bid < 128 : mean job (b = bid>>1, feat = bid&1); 8 waves split rows
//               (serial depth <= 4), LDS reduce, then 256 threads write
//               FP[(1+feat)*256 + t][b] (scattered 16B stores).
//   bid >= 128: first-token transpose for b = 2*(bid-128) + (t>>8);
//               t&255 -> quad q: FP[q][b] = hs[b,0,4q..4q+3].
__global__ __launch_bounds__(512) void feats_kernel(
    const float* __restrict__ hs,     // (B,S,H)
    const int*   __restrict__ subj,   // (B,2)
    const int*   __restrict__ obj,    // (B,2)
    float4*      __restrict__ FP)     // (768, 64) float4
{
    const int bid = blockIdx.x;
    const int tid = threadIdx.x;

    if (bid >= 128) {                 // first-token transpose (2 b per block)
        const int b = 2 * (bid - 128) + (tid >> 8);
        const int q = tid & 255;
        const float4 v = ((const float4*)(hs + (size_t)b * SS * HH))[q];
        FP[(size_t)q * BB + b] = v;
        return;
    }

    const int b    = bid >> 1;
    const int feat = bid & 1;
    const int* rng = feat ? obj : subj;
    const int s0 = rng[2 * b], s1 = rng[2 * b + 1];

    const int w    = tid >> 6;        // wave 0..7
    const int lane = tid & 63;

    __shared__ float4 lds[8][256];    // 8 wave-partials of H floats (32 KB)

    const float4* base = (const float4*)(hs + (size_t)b * SS * HH);

    float4 acc[4];                    // q -> float4 index q*64+lane
    #pragma unroll
    for (int q = 0; q < 4; ++q) acc[q] = make_float4(0.f, 0.f, 0.f, 0.f);

    for (int s = s0 + w; s < s1; s += 8) {
        const float4* row = base + (size_t)s * (HH / 4);
        #pragma unroll
        for (int q = 0; q < 4; ++q) {
            float4 v = row[q * 64 + lane];
            acc[q].x += v.x; acc[q].y += v.y; acc[q].z += v.z; acc[q].w += v.w;
        }
    }

    #pragma unroll
    for (int q = 0; q < 4; ++q)
        lds[w][q * 64 + lane] = acc[q];
    __syncthreads();

    if (tid < 256) {
        float4 s = lds[0][tid];
        #pragma unroll
        for (int p = 1; p < 8; ++p) {
            float4 v = lds[p][tid];
            s.x += v.x; s.y += v.y; s.z += v.z; s.w += v.w;
        }
        const float inv = 1.0f / fmaxf((float)(s1 - s0), 1.0f);
        s.x *= inv; s.y *= inv; s.z *= inv; s.w *= inv;
        FP[(size_t)((1 + feat) * 256 + tid) * BB + b] = s;   // scattered 16B
    }
}

// ---------------- Kernel 2: GEMM partials (NO LDS, NO barriers) -------------
// part[p][j][b] = sum_{k in chunk p} feats[b][k] * W[j][k]
// grid 1024 = (64 j-groups) x (16 k-parts), 256 threads = 4 waves.
// lane = b; wave owns RJ=4 j-columns.
//   feats: coalesced global_load_dwordx4 of FP[r][lane]  (vmcnt)
//   W    : wave-uniform rows -> s_load dwordx4/x8/x16    (lgkmcnt, no ds mix)
// Pure stream per wave: counted waits, no __syncthreads, tiny VGPR footprint.
__global__ __launch_bounds__(256) void gemm_kernel(
    const float4* __restrict__ FP,    // (768,64) float4
    const float*  __restrict__ W,     // (H,3H) row-major
    float*        __restrict__ part)  // (KSPLIT, H, B)
{
    const int bid   = blockIdx.x;
    const int kp    = bid & 15;
    const int jg    = bid >> 4;             // 0..63
    const int rbase = kp * (KCHUNK / 4);    // 48 rows per chunk
    const int tid   = threadIdx.x;

    const int w    = __builtin_amdgcn_readfirstlane(tid >> 6);  // 0..3 uniform
    const int lane = tid & 63;                                  // = batch b
    const int j0   = jg * JTILE + w * RJ;

    const float*  wp = W + (size_t)j0 * K3 + rbase * 4;         // uniform
    const float4* fp = FP + (size_t)rbase * BB + lane;

    float acc[RJ];
    #pragma unroll
    for (int jj = 0; jj < RJ; ++jj) acc[jj] = 0.f;

    #pragma unroll 4
    for (int r = 0; r < KCHUNK / 4; ++r) {                      // 48 rows
        const float4 f = fp[(size_t)r * BB];                    // coalesced
        #pragma unroll
        for (int jj = 0; jj < RJ; ++jj) {
            const float4 wv = *(const float4*)(wp + (size_t)jj * K3 + r * 4);
            acc[jj] = fmaf(f.x, wv.x, acc[jj]);
            acc[jj] = fmaf(f.y, wv.y, acc[jj]);
            acc[jj] = fmaf(f.z, wv.z, acc[jj]);
            acc[jj] = fmaf(f.w, wv.w, acc[jj]);
        }
    }

    float* pp = part + ((size_t)kp * HH + j0) * BB + lane;
    #pragma unroll
    for (int jj = 0; jj < RJ; ++jj)
        pp[jj * BB] = acc[jj];                      // coalesced over lanes
}

// ---------------- Kernel 3: reduce k-parts + bias + tanh --------------------
// grid 256 x 256: block covers 4 j-columns x 64 b.
__global__ __launch_bounds__(256) void reduce_kernel(
    const float* __restrict__ part,   // (KSPLIT, H, B)
    const float* __restrict__ bias,   // (H)
    float*       __restrict__ out)    // (B,H)
{
    const int t = threadIdx.x;
    const int j = blockIdx.x * 4 + (t >> 6);
    const int b = t & 63;
    float s = 0.f;
    #pragma unroll
    for (int p = 0; p < KSPLIT; ++p)
        s += part[((size_t)p * HH + j) * BB + b];   // coalesced over lanes
    out[(size_t)b * HH + j] = tanhf(s + bias[j]);
}

extern "C" void kernel_launch(void* const* d_in, const int* in_sizes, int n_in,
                              void* d_out, int out_size, void* d_ws, size_t ws_size,
                              hipStream_t stream) {
    const float* hs   = (const float*)d_in[0];  // (B,S,H) fp32
    const int*   subj = (const int*)d_in[1];    // (B,2) int32
    const int*   obj  = (const int*)d_in[2];    // (B,2) int32
    const float* W    = (const float*)d_in[3];  // (H,3H) fp32
    const float* bias = (const float*)d_in[4];  // (H) fp32
    float*       out  = (float*)d_out;          // (B,H) fp32

    float4* FP   = (float4*)d_ws;                           // 768 KB
    float*  part = (float*)((char*)d_ws + (1 << 20));       // 4 MB at +1 MB

    feats_kernel<<<160, 512, 0, stream>>>(hs, subj, obj, FP);
    gemm_kernel<<<(HH / JTILE) * KSPLIT, 256, 0, stream>>>(FP, W, part);
    reduce_kernel<<<HH / 4, 256, 0, stream>>>(part, bias, out);
}